// Round 9
// baseline (183.448 us; speedup 1.0000x reference)
//
#include <hip/hip_runtime.h>

#define IN_F   8192
#define OUT_F  8192
#define N_BLK  (OUT_F / 4)     // 2048 blocks, 4 rows/block
#define W_THRESH 50.0f
#define INHIB  0.5f

typedef float f32x4 __attribute__((ext_vector_type(4)));

// ---------------------------------------------------------------------------
// Single fused kernel, round-7 main loop + last-block-done epilogue.
//  - one wave per row, 4 rows/block (round 7: best k1, 6.4 TB/s)
//  - spikes preloaded to registers (sp[32], pure global stream, no lgkm in loop)
//  - each block finishes with ONE atomicAdd (no spinning — round-5 lesson);
//    the last block alone reduces the 2048 partials and does all 8192
//    v_mem/v_th updates (~160 KB, L2-hot, ~1 us) — kills dispatch #2's gap.
// ---------------------------------------------------------------------------
__global__ __launch_bounds__(256) void snn_fused_kernel(
    const float* __restrict__ spike,
    const float* __restrict__ states,
    const float* __restrict__ v_mem,
    const float* __restrict__ v_th,
    const float* __restrict__ noise,
    float* __restrict__ out,            // [spikes | v_mem_new | v_th_new]
    float* __restrict__ current,        // ws[0..8191]
    float* __restrict__ block_partial,  // ws[8192..10239]
    int*   __restrict__ g_count)        // ws+12288, zeroed each call
{
    __shared__ float s_f[4];
    __shared__ int   s_last;

    const int tid  = threadIdx.x;
    const int wave = tid >> 6;          // 0..3
    const int lane = tid & 63;
    const int row  = blockIdx.x * 4 + wave;

    const f32x4* sp4  = (const f32x4*)spike;
    const f32x4* row4 = (const f32x4*)(states + (size_t)row * IN_F);

    // preload this lane's 32 spike fragments (coalesced, static indexing)
    f32x4 sp[32];
    #pragma unroll
    for (int j = 0; j < 32; ++j)
        sp[j] = sp4[j * 64 + lane];

    float acc = 0.0f;
    // pure global stream: 32 coalesced dwordx4 per lane, no LDS in loop
    #pragma unroll
    for (int j = 0; j < 32; ++j) {
        const f32x4 s = row4[j * 64 + lane];
        acc += (s[0] > W_THRESH) ? sp[j][0] : 0.0f;
        acc += (s[1] > W_THRESH) ? sp[j][1] : 0.0f;
        acc += (s[2] > W_THRESH) ? sp[j][2] : 0.0f;
        acc += (s[3] > W_THRESH) ? sp[j][3] : 0.0f;
    }

    #pragma unroll
    for (int off = 32; off >= 1; off >>= 1)
        acc += __shfl_down(acc, off, 64);

    if (lane == 0) {
        const float c = acc;
        const float pot = v_mem[row] + c + noise[row];
        const float s = (pot >= v_th[row]) ? 1.0f : 0.0f;
        current[row] = c;
        out[row]     = s;
        s_f[wave]    = s;
    }
    __syncthreads();

    if (tid == 0) {
        block_partial[blockIdx.x] = s_f[0] + s_f[1] + s_f[2] + s_f[3];
        __threadfence();   // make this block's writes device-visible
        const int done = __hip_atomic_fetch_add(g_count, 1, __ATOMIC_ACQ_REL,
                                                __HIP_MEMORY_SCOPE_AGENT);
        s_last = (done == N_BLK - 1);
    }
    __syncthreads();
    if (!s_last) return;

    // ---- last block only: full epilogue (all prior writes visible) ----
    // sum of 2048 partials: 256 threads x 2 f32x4
    {
        __shared__ float s_part[4];
        const f32x4* bp4 = (const f32x4*)block_partial;
        float local = 0.0f;
        #pragma unroll
        for (int k = 0; k < 2; ++k) {
            f32x4 v = bp4[tid + k * 256];
            local += v[0] + v[1] + v[2] + v[3];
        }
        #pragma unroll
        for (int off = 32; off >= 1; off >>= 1)
            local += __shfl_down(local, off, 64);
        if ((tid & 63) == 0) s_part[tid >> 6] = local;
        __syncthreads();

        const float inh = (s_part[0] + s_part[1] + s_part[2] + s_part[3]) * INHIB;

        // 8192 outputs / 256 threads = 32 each, strided for coalescing
        #pragma unroll
        for (int k = 0; k < 32; ++k) {
            const int o = tid + k * 256;
            const float s = out[o];
            const float vnew = (v_mem[o] - inh + current[o]) * (1.0f - s) * 0.5f;
            out[OUT_F + o] = vnew;
            float tnew = v_th[o] + (s - 0.1f) * 0.01f;
            out[2 * OUT_F + o] = fminf(fmaxf(tnew, 0.2f), 5.0f);
        }
    }
}

// ---------------------------------------------------------------------------
extern "C" void kernel_launch(void* const* d_in, const int* in_sizes, int n_in,
                              void* d_out, int out_size, void* d_ws, size_t ws_size,
                              hipStream_t stream)
{
    const float* spike  = (const float*)d_in[0];  // [1, 8192]
    const float* states = (const float*)d_in[1];  // [8192, 8192]
    const float* v_mem  = (const float*)d_in[2];  // [8192]
    const float* v_th   = (const float*)d_in[3];  // [8192]
    const float* noise  = (const float*)d_in[4];  // [8192]
    float* out = (float*)d_out;                   // [3 * 8192]

    float* current       = (float*)d_ws;                    // ws[0..8191]
    float* block_partial = (float*)d_ws + OUT_F;            // ws[8192..10239]
    int*   g_count       = (int*)((char*)d_ws + 12288 * 4); // own region

    // zero the completion counter each call (graph-capturable memset node)
    hipMemsetAsync(g_count, 0, 4, stream);

    snn_fused_kernel<<<N_BLK, 256, 0, stream>>>(
        spike, states, v_mem, v_th, noise, out, current, block_partial, g_count);
}

// Round 10
// 44.571 us; speedup vs baseline: 4.1159x; 4.1159x over previous
//
#include <hip/hip_runtime.h>

#define IN_F   8192
#define OUT_F  8192
#define N_BLK  (OUT_F / 4)     // 2048 blocks in kernel 1
#define W_THRESH 50.0f
#define INHIB  0.5f

typedef float f32x4 __attribute__((ext_vector_type(4)));

// ---------------------------------------------------------------------------
// Kernel 1 (round-7 config — best measured, 6.36 TB/s demand BW):
// current[o] = sum_i spike[i] * (state[o][i] > 50), per-row spike decision,
// and a per-block spike partial for kernel 2.
// One wave per output row; 4 rows per 256-thread block.
// Spike fragments hoisted out of the loop (compiler keeps them L1-hot /
// partially in regs); inner loop is a pure coalesced global stream — no
// ds_read/lgkm waits (round 6->7 A/B: -1.2 us vs LDS staging).
// NO cross-block sync in-kernel: per-block agent-scope fences cost ~150+ us
// on this chip (L2 wb-inv per block, rounds 5 & 9) — kernel boundary is the
// only affordable device-wide barrier.
// ---------------------------------------------------------------------------
__global__ __launch_bounds__(256) void snn_current_kernel(
    const float* __restrict__ spike,
    const float* __restrict__ states,
    const float* __restrict__ v_mem,
    const float* __restrict__ v_th,
    const float* __restrict__ noise,
    float* __restrict__ current,        // ws[0..8191]
    float* __restrict__ out_spikes,     // out[0..8191]
    float* __restrict__ block_partial)  // ws[8192..10239]
{
    __shared__ float s_f[4];            // 16 B cross-wave scratch only

    const int tid  = threadIdx.x;
    const int wave = tid >> 6;          // 0..3
    const int lane = tid & 63;
    const int row  = blockIdx.x * 4 + wave;

    const f32x4* sp4  = (const f32x4*)spike;
    const f32x4* row4 = (const f32x4*)(states + (size_t)row * IN_F);

    // hoisted spike fragment loads (coalesced; L1-resident across the block)
    f32x4 sp[32];
    #pragma unroll
    for (int j = 0; j < 32; ++j)
        sp[j] = sp4[j * 64 + lane];

    float acc = 0.0f;
    // pure global stream: 32 coalesced dwordx4 per lane
    #pragma unroll
    for (int j = 0; j < 32; ++j) {
        const f32x4 s = row4[j * 64 + lane];
        acc += (s[0] > W_THRESH) ? sp[j][0] : 0.0f;
        acc += (s[1] > W_THRESH) ? sp[j][1] : 0.0f;
        acc += (s[2] > W_THRESH) ? sp[j][2] : 0.0f;
        acc += (s[3] > W_THRESH) ? sp[j][3] : 0.0f;
    }

    // 64-lane butterfly reduction
    #pragma unroll
    for (int off = 32; off >= 1; off >>= 1)
        acc += __shfl_down(acc, off, 64);

    if (lane == 0) {
        const float c = acc;
        const float pot = v_mem[row] + c + noise[row];
        const float s = (pot >= v_th[row]) ? 1.0f : 0.0f;
        current[row]    = c;
        out_spikes[row] = s;
        s_f[wave]       = s;
    }
    __syncthreads();
    if (tid == 0)
        block_partial[blockIdx.x] = s_f[0] + s_f[1] + s_f[2] + s_f[3];
}

// ---------------------------------------------------------------------------
// Kernel 2: v_mem / v_th updates. Each block redundantly reduces the 2048
// per-block partials (8 KB, L2-resident; exact small integers) to get
// sum(spikes) without atomics, then handles its 256-element slice.
// out layout: [spikes(8192) | v_mem_new(8192) | v_th_new(8192)]
// ---------------------------------------------------------------------------
__global__ __launch_bounds__(256) void snn_update_kernel(
    const float* __restrict__ current,
    const float* __restrict__ v_mem,
    const float* __restrict__ v_th,
    const float* __restrict__ spikes,         // == out[0..8191]
    const float* __restrict__ block_partial,  // ws[8192..10239]
    float* __restrict__ out)
{
    __shared__ float s_part[4];

    const int tid = threadIdx.x;

    // sum of 2048 partials: 256 threads x 2 f32x4 each
    const f32x4* bp4 = (const f32x4*)block_partial;
    float local = 0.0f;
    #pragma unroll
    for (int k = 0; k < 2; ++k) {
        f32x4 v = bp4[tid + k * 256];
        local += v[0] + v[1] + v[2] + v[3];
    }
    #pragma unroll
    for (int off = 32; off >= 1; off >>= 1)
        local += __shfl_down(local, off, 64);
    if ((tid & 63) == 0) s_part[tid >> 6] = local;
    __syncthreads();

    const float total = s_part[0] + s_part[1] + s_part[2] + s_part[3];
    const float inhibition = total * INHIB;

    const int o = blockIdx.x * 256 + tid;
    const float s = spikes[o];
    const float vnew = (v_mem[o] - inhibition + current[o]) * (1.0f - s) * 0.5f;
    out[OUT_F + o] = vnew;
    float tnew = v_th[o] + (s - 0.1f) * 0.01f;
    tnew = fminf(fmaxf(tnew, 0.2f), 5.0f);
    out[2 * OUT_F + o] = tnew;
}

// ---------------------------------------------------------------------------
extern "C" void kernel_launch(void* const* d_in, const int* in_sizes, int n_in,
                              void* d_out, int out_size, void* d_ws, size_t ws_size,
                              hipStream_t stream)
{
    const float* spike  = (const float*)d_in[0];  // [1, 8192]
    const float* states = (const float*)d_in[1];  // [8192, 8192]
    const float* v_mem  = (const float*)d_in[2];  // [8192]
    const float* v_th   = (const float*)d_in[3];  // [8192]
    const float* noise  = (const float*)d_in[4];  // [8192]
    float* out = (float*)d_out;                   // [3 * 8192]

    float* current       = (float*)d_ws;          // ws[0..8191]
    float* block_partial = (float*)d_ws + OUT_F;  // ws[8192..10239]

    snn_current_kernel<<<N_BLK, 256, 0, stream>>>(
        spike, states, v_mem, v_th, noise, current, out, block_partial);
    snn_update_kernel<<<OUT_F / 256, 256, 0, stream>>>(
        current, v_mem, v_th, out, block_partial, out);
}